// Round 1
// baseline (222039.233 us; speedup 1.0000x reference)
//
#include <hip/hip_runtime.h>
#include <math.h>

#define L_SEQ 1024
#define EPSBN 1e-5f

// ===================== conv + BN (training-mode batch stats) =====================

template<int CI, int COT, int TL>
__global__ __launch_bounds__(256) void conv_k(const float* __restrict__ in,
                                              const float* __restrict__ w,
                                              float* __restrict__ out, int CO) {
  static_assert(COT * TL == 256, "block mismatch");
  __shared__ float s_in[TL + 6][CI + 1];
  const int cog = blockIdx.x, lt = blockIdx.y, b = blockIdx.z;
  const int l0 = lt * TL;
  for (int i = threadIdx.x; i < (TL + 6) * CI; i += 256) {
    const int r = i / CI, c = i - r * CI;
    const int l = l0 + r - 3;
    s_in[r][c] = (l >= 0 && l < L_SEQ) ? in[(b * L_SEQ + l) * CI + c] : 0.f;
  }
  __syncthreads();
  const int lo = threadIdx.x / COT, coo = threadIdx.x % COT;
  const int co = cog * COT + coo;
  const float* wr = w + co * (CI * 7);
  float acc = 0.f;
  for (int ci = 0; ci < CI; ++ci) {
    const float* wc = wr + ci * 7;
#pragma unroll
    for (int k = 0; k < 7; ++k) acc = fmaf(s_in[lo + k][ci], wc[k], acc);
  }
  out[(b * L_SEQ + l0 + lo) * CO + co] = acc;
}

template<int C>
__global__ __launch_bounds__(256) void bn_stats_k(const float* __restrict__ x,
                                                  float* __restrict__ sums, int n) {
  float s = 0.f, q = 0.f;
  const int stride = gridDim.x * 256;
  for (int i = blockIdx.x * 256 + threadIdx.x; i < n; i += stride) {
    const float v = x[i];
    s += v;
    q = fmaf(v, v, q);
  }
  __shared__ float ss[256], sq[256];
  ss[threadIdx.x] = s; sq[threadIdx.x] = q;
  __syncthreads();
#pragma unroll
  for (int off = 128; off >= C; off >>= 1) {
    if (threadIdx.x < off) {
      ss[threadIdx.x] += ss[threadIdx.x + off];
      sq[threadIdx.x] += sq[threadIdx.x + off];
    }
    __syncthreads();
  }
  if (threadIdx.x < C) {
    atomicAdd(&sums[threadIdx.x], ss[threadIdx.x]);
    atomicAdd(&sums[256 + threadIdx.x], sq[threadIdx.x]);
  }
}

template<int C>
__global__ __launch_bounds__(256) void bn_norm_k(float* __restrict__ x,
                                                 const float* __restrict__ sums,
                                                 const float* __restrict__ g,
                                                 const float* __restrict__ bt, int n4) {
  const float invN = 1.f / 131072.f;  // B*L
  const int stride = gridDim.x * 256;
  for (int i = blockIdx.x * 256 + threadIdx.x; i < n4; i += stride) {
    float4 v = ((const float4*)x)[i];
    const int c0 = (i * 4) % C;
    float r[4] = {v.x, v.y, v.z, v.w};
#pragma unroll
    for (int j = 0; j < 4; ++j) {
      const int c = c0 + j;
      const float m = sums[c] * invN;
      const float var = fmaf(-m, m, sums[256 + c] * invN);
      const float y = g[c] * (r[j] - m) * rsqrtf(var + EPSBN) + bt[c];
      r[j] = fmaxf(y, 0.f);
    }
    ((float4*)x)[i] = make_float4(r[0], r[1], r[2], r[3]);
  }
}

// ===================== persistent LSTM (layer 0 only: layer 1 is dead code) =====================

struct LP {
  const float* Wx_e; const float* Wh_e; const float* bi_e; const float* bh_e;
  const float* Wx_d; const float* Wh_d; const float* bi_d; const float* bh_d;
  const float* oW;   const float* ob;
  float* x;          // d_out: conv3-normalized features, later overwritten with outputs
  float* h0g;        // [2][128][512] ping-pong hidden state
  unsigned* bar;     // barrier counters: 4 groups x (cnt, gen)
};

__device__ __forceinline__ float sigm(float v) { return 1.f / (1.f + __expf(-v)); }

// barrier among the 64 WGs of one batch-group (device-scope atomics; cross-XCD safe)
__device__ __forceinline__ void gbar(unsigned* cnt, unsigned* gen) {
  __syncthreads();
  if (threadIdx.x == 0) {
    __threadfence();  // release: drain WG stores to device coherence point
    const unsigned g = __hip_atomic_load(gen, __ATOMIC_RELAXED, __HIP_MEMORY_SCOPE_AGENT);
    if (__hip_atomic_fetch_add(cnt, 1u, __ATOMIC_ACQ_REL, __HIP_MEMORY_SCOPE_AGENT) == 63u) {
      __hip_atomic_store(cnt, 0u, __ATOMIC_RELAXED, __HIP_MEMORY_SCOPE_AGENT);
      __hip_atomic_store(gen, g + 1u, __ATOMIC_RELEASE, __HIP_MEMORY_SCOPE_AGENT);
    } else {
      unsigned cur;
      do {
        __builtin_amdgcn_s_sleep(4);
        cur = __hip_atomic_load(gen, __ATOMIC_RELAXED, __HIP_MEMORY_SCOPE_AGENT);
      } while (cur == g);
      __threadfence();  // acquire: invalidate stale caches once after wakeup
    }
  }
  __syncthreads();
}

// stage a [32 rows x 256 floats] tile into LDS (padded stride 264)
__device__ __forceinline__ void stage256(float (*dst)[264], const float* src, int rstride) {
#pragma unroll
  for (int r = 0; r < 4; ++r) {
    const int fid = threadIdx.x + r * 512;
    const int row = fid >> 6, c4 = (fid & 63) << 2;
    *(float4*)(&dst[row][c4]) = *(const float4*)(src + row * rstride + c4);
  }
}

// 256-long K-chunk of two gate dot-products (dual accumulators for ILP)
__device__ __forceinline__ void kloop(float& aA0, float& aA1, float& aB0, float& aB1,
                                      const float (*buf)[264], int bo,
                                      const float4* __restrict__ wA,
                                      const float4* __restrict__ wB) {
  const float4* a4 = (const float4*)(&buf[bo][0]);
#pragma unroll 8
  for (int j = 0; j < 64; ++j) {
    const float4 a = a4[j], u = wA[j], v = wB[j];
    aA0 = fmaf(a.x, u.x, aA0); aA1 = fmaf(a.y, u.y, aA1);
    aA0 = fmaf(a.z, u.z, aA0); aA1 = fmaf(a.w, u.w, aA1);
    aB0 = fmaf(a.x, v.x, aB0); aB1 = fmaf(a.y, v.y, aB1);
    aB0 = fmaf(a.z, v.z, aB0); aB1 = fmaf(a.w, v.w, aB1);
  }
}

__global__ __launch_bounds__(512, 1) void lstm_k(LP p) {
  const int wgid = blockIdx.x;
  const int bg = wgid >> 6;         // batch group 0..3 (32 rows each) — independent groups
  const int cg = wgid & 63;         // hidden-slice group: 8 hidden units x 4 gates = 32 cols
  const int tid = threadIdx.x;
  const int h8 = tid & 7, gp = (tid >> 3) & 1, bo = tid >> 4;
  const int b = bg * 32 + bo;
  const int hid = cg * 8 + h8;
  const int rA = gp * 1024 + hid;   // gp=0: gates i,f ; gp=1: gates g,o
  const int rB = rA + 512;

  __shared__ float buf[32][264];

  unsigned* cnt = p.bar + bg * 32;
  unsigned* gen = cnt + 16;

  // zero-init the parity-1 hidden buffer (read at tick 0)
  if (gp == 0) p.h0g[65536 + b * 512 + hid] = 0.f;

  float cst = 0.f;  // cell state, lives in a register across all 2048 steps (gp==0 lanes)

  const float biasAe = p.bi_e[rA] + p.bh_e[rA];
  const float biasBe = p.bi_e[rB] + p.bh_e[rB];
  const float4* WxAe = (const float4*)(p.Wx_e + rA * 256);
  const float4* WxBe = (const float4*)(p.Wx_e + rB * 256);
  const float4* WhAe = (const float4*)(p.Wh_e + rA * 512);
  const float4* WhBe = (const float4*)(p.Wh_e + rB * 512);

  const float* xrow = p.x + bg * 32 * (L_SEQ * 256);

  gbar(cnt, gen);

  // ---------------- encoder (layer 0 only) ----------------
  for (int k = 0; k < 1024; ++k) {
    const int par_r = (k + 1) & 1, par_w = k & 1;
    float aA0 = biasAe, aA1 = 0.f, aB0 = biasBe, aB1 = 0.f;

    stage256(buf, xrow + k * 256, L_SEQ * 256);
    __syncthreads();
    kloop(aA0, aA1, aB0, aB1, buf, bo, WxAe, WxBe);
    __syncthreads();

    const float* hbase = p.h0g + par_r * 65536 + bg * 32 * 512;
    stage256(buf, hbase, 512);
    __syncthreads();
    kloop(aA0, aA1, aB0, aB1, buf, bo, WhAe, WhBe);
    __syncthreads();
    stage256(buf, hbase + 256, 512);
    __syncthreads();
    kloop(aA0, aA1, aB0, aB1, buf, bo, WhAe + 64, WhBe + 64);

    const float accA = aA0 + aA1, accB = aB0 + aB1;
    const float gg = __shfl_xor(accA, 8);
    const float oo = __shfl_xor(accB, 8);
    if (gp == 0) {
      const float iv = sigm(accA), fv = sigm(accB), gv = tanhf(gg), ov = sigm(oo);
      cst = fmaf(fv, cst, iv * gv);
      p.h0g[par_w * 65536 + b * 512 + hid] = ov * tanhf(cst);
    }
    gbar(cnt, gen);
  }

  // ---------------- decoder (layer 0 + out-proj; out[t] written one tick late) ----------------
  const float biasAd = p.bi_d[rA] + p.bh_d[rA];
  const float biasBd = p.bi_d[rB] + p.bh_d[rB];
  const float4* WxAd = (const float4*)(p.Wx_d + rA * 256);
  const float4* WxBd = (const float4*)(p.Wx_d + rB * 256);
  const float4* WhAd = (const float4*)(p.Wh_d + rA * 512);
  const float4* WhBd = (const float4*)(p.Wh_d + rB * 512);
  const int ob = tid >> 2, oco = tid & 3;  // used by tid<128: 32 batch x 4 out-cols
  const int oc = cg * 4 + oco;
  const float4* oWr = (const float4*)(p.oW + oc * 512);
  float out_prev = 0.f;

  for (int k = 0; k < 1024; ++k) {
    const int t = 1023 - k;
    const int par_r = (k + 1) & 1, par_w = k & 1;
    float aA0 = biasAd, aA1 = 0.f, aB0 = biasBd, aB1 = 0.f;
    float po0 = 0.f, po1 = 0.f;

    // write out[t+1] computed last tick (races impossible: this tick everyone reads x[t])
    if (k > 0 && tid < 128)
      p.x[((bg * 32 + ob) * L_SEQ + (t + 1)) * 256 + oc] = out_prev;

    stage256(buf, xrow + t * 256, L_SEQ * 256);
    __syncthreads();
    kloop(aA0, aA1, aB0, aB1, buf, bo, WxAd, WxBd);
    __syncthreads();

    const float* hbase = p.h0g + par_r * 65536 + bg * 32 * 512;
    stage256(buf, hbase, 512);
    __syncthreads();
    kloop(aA0, aA1, aB0, aB1, buf, bo, WhAd, WhBd);
    if (tid < 128) {  // out-proj chunk 0 (uses same staged pre-step h0)
      const float4* hb4 = (const float4*)(&buf[ob][0]);
#pragma unroll 8
      for (int j = 0; j < 64; ++j) {
        const float4 a = hb4[j], u = oWr[j];
        po0 = fmaf(a.x, u.x, po0); po1 = fmaf(a.y, u.y, po1);
        po0 = fmaf(a.z, u.z, po0); po1 = fmaf(a.w, u.w, po1);
      }
    }
    __syncthreads();
    stage256(buf, hbase + 256, 512);
    __syncthreads();
    kloop(aA0, aA1, aB0, aB1, buf, bo, WhAd + 64, WhBd + 64);
    if (tid < 128) {  // out-proj chunk 1
      const float4* hb4 = (const float4*)(&buf[ob][0]);
#pragma unroll 8
      for (int j = 0; j < 64; ++j) {
        const float4 a = hb4[j], u = oWr[64 + j];
        po0 = fmaf(a.x, u.x, po0); po1 = fmaf(a.y, u.y, po1);
        po0 = fmaf(a.z, u.z, po0); po1 = fmaf(a.w, u.w, po1);
      }
    }

    const float accA = aA0 + aA1, accB = aB0 + aB1;
    const float gg = __shfl_xor(accA, 8);
    const float oo = __shfl_xor(accB, 8);
    if (gp == 0) {
      const float iv = sigm(accA), fv = sigm(accB), gv = tanhf(gg), ov = sigm(oo);
      cst = fmaf(fv, cst, iv * gv);
      p.h0g[par_w * 65536 + b * 512 + hid] = ov * tanhf(cst);
    }
    out_prev = po0 + po1 + p.ob[oc];
    gbar(cnt, gen);
  }
  if (tid < 128)  // final output (t = 0)
    p.x[((bg * 32 + ob) * L_SEQ + 0) * 256 + oc] = out_prev;
}

// ===================== launch =====================

extern "C" void kernel_launch(void* const* d_in, const int* in_sizes, int n_in,
                              void* d_out, int out_size, void* d_ws, size_t ws_size,
                              hipStream_t stream) {
  (void)in_sizes; (void)n_in; (void)out_size; (void)ws_size;

  const float* x_in = (const float*)d_in[0];
  const float* c1w  = (const float*)d_in[1];
  const float* bn1g = (const float*)d_in[2];
  const float* bn1b = (const float*)d_in[3];
  const float* c2w  = (const float*)d_in[4];
  const float* bn2g = (const float*)d_in[5];
  const float* bn2b = (const float*)d_in[6];
  const float* c3w  = (const float*)d_in[7];
  const float* bn3g = (const float*)d_in[8];
  const float* bn3b = (const float*)d_in[9];
  const float* eWx0 = (const float*)d_in[10];
  const float* eWh0 = (const float*)d_in[11];
  const float* ebi0 = (const float*)d_in[12];
  const float* ebh0 = (const float*)d_in[13];
  // enc layer-1 params (14..17) and dec layer-1 params (22..25) are dead code
  const float* dWx0 = (const float*)d_in[18];
  const float* dWh0 = (const float*)d_in[19];
  const float* dbi0 = (const float*)d_in[20];
  const float* dbh0 = (const float*)d_in[21];
  const float* oW   = (const float*)d_in[26];
  const float* obv  = (const float*)d_in[27];

  float* out = (float*)d_out;
  float* A     = (float*)d_ws;            // conv1 out: 128*1024*32
  float* Bb    = A + 4194304;             // conv2 out: 128*1024*64
  float* stats = Bb + 8388608;            // 512 floats (sum, sumsq)
  float* h0g   = stats + 512;             // 2*128*512
  unsigned* bar = (unsigned*)(h0g + 131072);  // 128 uints

  // ---- conv1 + BN + ReLU ----
  hipMemsetAsync(stats, 0, 512 * sizeof(float), stream);
  conv_k<32, 32, 8><<<dim3(1, 128, 128), 256, 0, stream>>>(x_in, c1w, A, 32);
  bn_stats_k<32><<<1024, 256, 0, stream>>>(A, stats, 4194304);
  bn_norm_k<32><<<2048, 256, 0, stream>>>(A, stats, bn1g, bn1b, 1048576);

  // ---- conv2 + BN + ReLU ----
  hipMemsetAsync(stats, 0, 512 * sizeof(float), stream);
  conv_k<32, 64, 4><<<dim3(1, 256, 128), 256, 0, stream>>>(A, c2w, Bb, 64);
  bn_stats_k<64><<<1024, 256, 0, stream>>>(Bb, stats, 8388608);
  bn_norm_k<64><<<2048, 256, 0, stream>>>(Bb, stats, bn2g, bn2b, 2097152);

  // ---- conv3 + BN + ReLU (written straight into d_out; used as teacher input x) ----
  hipMemsetAsync(stats, 0, 512 * sizeof(float), stream);
  conv_k<64, 64, 4><<<dim3(4, 256, 128), 256, 0, stream>>>(Bb, c3w, out, 256);
  bn_stats_k<256><<<1024, 256, 0, stream>>>(out, stats, 33554432);
  bn_norm_k<256><<<4096, 256, 0, stream>>>(out, stats, bn3g, bn3b, 8388608);

  // ---- persistent LSTM enc+dec ----
  hipMemsetAsync(bar, 0, 128 * sizeof(unsigned), stream);
  LP lp{eWx0, eWh0, ebi0, ebh0, dWx0, dWh0, dbi0, dbh0, oW, obv, out, h0g, bar};
  void* kargs[] = {&lp};
  hipLaunchCooperativeKernel((const void*)lstm_k, dim3(256), dim3(512), kargs, 0, stream);
}

// Round 3
// 209129.443 us; speedup vs baseline: 1.0617x; 1.0617x over previous
//
#include <hip/hip_runtime.h>
#include <math.h>

#define L_SEQ 1024
#define EPSBN 1e-5f

// ===================== conv + BN (training-mode batch stats) =====================

template<int CI, int COT, int TL>
__global__ __launch_bounds__(256) void conv_k(const float* __restrict__ in,
                                              const float* __restrict__ w,
                                              float* __restrict__ out, int CO) {
  static_assert(COT * TL == 256, "block mismatch");
  __shared__ float s_in[TL + 6][CI + 1];
  const int cog = blockIdx.x, lt = blockIdx.y, b = blockIdx.z;
  const int l0 = lt * TL;
  for (int i = threadIdx.x; i < (TL + 6) * CI; i += 256) {
    const int r = i / CI, c = i - r * CI;
    const int l = l0 + r - 3;
    s_in[r][c] = (l >= 0 && l < L_SEQ) ? in[(b * L_SEQ + l) * CI + c] : 0.f;
  }
  __syncthreads();
  const int lo = threadIdx.x / COT, coo = threadIdx.x % COT;
  const int co = cog * COT + coo;
  const float* wr = w + co * (CI * 7);
  float acc = 0.f;
  for (int ci = 0; ci < CI; ++ci) {
    const float* wc = wr + ci * 7;
#pragma unroll
    for (int k = 0; k < 7; ++k) acc = fmaf(s_in[lo + k][ci], wc[k], acc);
  }
  out[(b * L_SEQ + l0 + lo) * CO + co] = acc;
}

template<int C>
__global__ __launch_bounds__(256) void bn_stats_k(const float* __restrict__ x,
                                                  float* __restrict__ sums, int n) {
  float s = 0.f, q = 0.f;
  const int stride = gridDim.x * 256;
  for (int i = blockIdx.x * 256 + threadIdx.x; i < n; i += stride) {
    const float v = x[i];
    s += v;
    q = fmaf(v, v, q);
  }
  __shared__ float ss[256], sq[256];
  ss[threadIdx.x] = s; sq[threadIdx.x] = q;
  __syncthreads();
#pragma unroll
  for (int off = 128; off >= C; off >>= 1) {
    if (threadIdx.x < off) {
      ss[threadIdx.x] += ss[threadIdx.x + off];
      sq[threadIdx.x] += sq[threadIdx.x + off];
    }
    __syncthreads();
  }
  if (threadIdx.x < C) {
    atomicAdd(&sums[threadIdx.x], ss[threadIdx.x]);
    atomicAdd(&sums[256 + threadIdx.x], sq[threadIdx.x]);
  }
}

template<int C>
__global__ __launch_bounds__(256) void bn_norm_k(float* __restrict__ x,
                                                 const float* __restrict__ sums,
                                                 const float* __restrict__ g,
                                                 const float* __restrict__ bt, int n4) {
  const float invN = 1.f / 131072.f;  // B*L
  const int stride = gridDim.x * 256;
  for (int i = blockIdx.x * 256 + threadIdx.x; i < n4; i += stride) {
    float4 v = ((const float4*)x)[i];
    const int c0 = (i * 4) % C;
    float r[4] = {v.x, v.y, v.z, v.w};
#pragma unroll
    for (int j = 0; j < 4; ++j) {
      const int c = c0 + j;
      const float m = sums[c] * invN;
      const float var = fmaf(-m, m, sums[256 + c] * invN);
      const float y = g[c] * (r[j] - m) * rsqrtf(var + EPSBN) + bt[c];
      r[j] = fmaxf(y, 0.f);
    }
    ((float4*)x)[i] = make_float4(r[0], r[1], r[2], r[3]);
  }
}

// ===================== persistent LSTM (layer 0 only: layer 1 is dead code) =====================

struct LP {
  const float* Wx_e; const float* Wh_e; const float* bi_e; const float* bh_e;
  const float* Wx_d; const float* Wh_d; const float* bi_d; const float* bh_d;
  const float* oW;   const float* ob;
  float* x;          // d_out: conv3-normalized features, later overwritten with outputs
  float* h0g;        // [2][128][512] ping-pong hidden state (agent-scope sc1 traffic only)
  unsigned* flags;   // 4 groups x 64 per-WG monotonic tick flags (no RMW, no reset)
};

__device__ __forceinline__ float sigm(float v) { return 1.f / (1.f + __expf(-v)); }

// Fence-free flag barrier among the 64 WGs of one batch-group.
// Ordering argument: __syncthreads() makes the compiler drain vmcnt(0) per wave
// (all sc1 h-stores acked at the coherence point) BEFORE s_barrier; only then does
// thread 0 publish the monotonic tick. Readers touch h exclusively through
// agent-scope (cache-bypassing) loads, so no acquire fence / L2 invalidate needed.
__device__ __forceinline__ void gbar(unsigned* flags, int me, unsigned tick) {
  __syncthreads();
  if (threadIdx.x < 64) {
    if (threadIdx.x == 0)
      __hip_atomic_store(flags + me, tick, __ATOMIC_RELAXED, __HIP_MEMORY_SCOPE_AGENT);
    __builtin_amdgcn_sched_barrier(0);
    unsigned f = __hip_atomic_load(flags + threadIdx.x, __ATOMIC_RELAXED, __HIP_MEMORY_SCOPE_AGENT);
    while (!__all(f >= tick)) {
      __builtin_amdgcn_s_sleep(2);
      f = __hip_atomic_load(flags + threadIdx.x, __ATOMIC_RELAXED, __HIP_MEMORY_SCOPE_AGENT);
    }
  }
  __syncthreads();
}

// stage a [32 rows x 256 floats] tile into LDS (padded stride 264) — plain cached loads
__device__ __forceinline__ void stage256(float (*dst)[264], const float* src, int rstride) {
#pragma unroll
  for (int r = 0; r < 4; ++r) {
    const int fid = threadIdx.x + r * 512;
    const int row = fid >> 6, c4 = (fid & 63) << 2;
    *(float4*)(&dst[row][c4]) = *(const float4*)(src + row * rstride + c4);
  }
}

// stage a [32 rows x 256 floats] h-tile via agent-scope loads (bypass stale L1/L2)
__device__ __forceinline__ void stage_h(float (*dst)[264], const float* src, int rstride) {
#pragma unroll
  for (int r = 0; r < 16; ++r) {
    const int fid = threadIdx.x + r * 512;
    const int row = fid >> 8, c = fid & 255;
    dst[row][c] = __hip_atomic_load(src + row * rstride + c,
                                    __ATOMIC_RELAXED, __HIP_MEMORY_SCOPE_AGENT);
  }
}

// 256-long K-chunk of two gate dot-products (dual accumulators for ILP)
__device__ __forceinline__ void kloop(float& aA0, float& aA1, float& aB0, float& aB1,
                                      const float (*buf)[264], int bo,
                                      const float4* __restrict__ wA,
                                      const float4* __restrict__ wB) {
  const float4* a4 = (const float4*)(&buf[bo][0]);
#pragma unroll 8
  for (int j = 0; j < 64; ++j) {
    const float4 a = a4[j], u = wA[j], v = wB[j];
    aA0 = fmaf(a.x, u.x, aA0); aA1 = fmaf(a.y, u.y, aA1);
    aA0 = fmaf(a.z, u.z, aA0); aA1 = fmaf(a.w, u.w, aA1);
    aB0 = fmaf(a.x, v.x, aB0); aB1 = fmaf(a.y, v.y, aB1);
    aB0 = fmaf(a.z, v.z, aB0); aB1 = fmaf(a.w, v.w, aB1);
  }
}

__global__ __launch_bounds__(512, 1) void lstm_k(LP p) {
  const int wgid = blockIdx.x;
  const int bg = wgid >> 6;         // batch group 0..3 (32 rows each) — independent groups
  const int cg = wgid & 63;         // hidden-slice group: 8 hidden units x 4 gates = 32 cols
  const int tid = threadIdx.x;
  const int h8 = tid & 7, gp = (tid >> 3) & 1, bo = tid >> 4;
  const int b = bg * 32 + bo;
  const int hid = cg * 8 + h8;
  const int rA = gp * 1024 + hid;   // gp=0: gates i,f ; gp=1: gates g,o
  const int rB = rA + 512;

  __shared__ float buf[32][264];

  unsigned* flags = p.flags + bg * 64;
  unsigned tick = 1;

  // zero-init the parity-1 hidden buffer (read at tick 0) via agent-scope stores
  if (gp == 0)
    __hip_atomic_store(p.h0g + 65536 + b * 512 + hid, 0.f,
                       __ATOMIC_RELAXED, __HIP_MEMORY_SCOPE_AGENT);

  float cst = 0.f;  // cell state, lives in a register across all 2048 steps (gp==0 lanes)

  const float biasAe = p.bi_e[rA] + p.bh_e[rA];
  const float biasBe = p.bi_e[rB] + p.bh_e[rB];
  const float4* WxAe = (const float4*)(p.Wx_e + rA * 256);
  const float4* WxBe = (const float4*)(p.Wx_e + rB * 256);
  const float4* WhAe = (const float4*)(p.Wh_e + rA * 512);
  const float4* WhBe = (const float4*)(p.Wh_e + rB * 512);

  const float* xrow = p.x + bg * 32 * (L_SEQ * 256);

  gbar(flags, cg, tick); ++tick;

  // ---------------- encoder (layer 0 only) ----------------
  for (int k = 0; k < 1024; ++k) {
    const int par_r = (k + 1) & 1, par_w = k & 1;
    float aA0 = biasAe, aA1 = 0.f, aB0 = biasBe, aB1 = 0.f;

    stage256(buf, xrow + k * 256, L_SEQ * 256);
    __syncthreads();
    kloop(aA0, aA1, aB0, aB1, buf, bo, WxAe, WxBe);
    __syncthreads();

    const float* hbase = p.h0g + par_r * 65536 + bg * 32 * 512;
    stage_h(buf, hbase, 512);
    __syncthreads();
    kloop(aA0, aA1, aB0, aB1, buf, bo, WhAe, WhBe);
    __syncthreads();
    stage_h(buf, hbase + 256, 512);
    __syncthreads();
    kloop(aA0, aA1, aB0, aB1, buf, bo, WhAe + 64, WhBe + 64);

    const float accA = aA0 + aA1, accB = aB0 + aB1;
    const float gg = __shfl_xor(accA, 8);
    const float oo = __shfl_xor(accB, 8);
    if (gp == 0) {
      const float iv = sigm(accA), fv = sigm(accB), gv = tanhf(gg), ov = sigm(oo);
      cst = fmaf(fv, cst, iv * gv);
      __hip_atomic_store(p.h0g + par_w * 65536 + b * 512 + hid, ov * tanhf(cst),
                         __ATOMIC_RELAXED, __HIP_MEMORY_SCOPE_AGENT);
    }
    gbar(flags, cg, tick); ++tick;
  }

  // ---------------- decoder (layer 0 + out-proj; out[t] written one tick late) ----------------
  const float biasAd = p.bi_d[rA] + p.bh_d[rA];
  const float biasBd = p.bi_d[rB] + p.bh_d[rB];
  const float4* WxAd = (const float4*)(p.Wx_d + rA * 256);
  const float4* WxBd = (const float4*)(p.Wx_d + rB * 256);
  const float4* WhAd = (const float4*)(p.Wh_d + rA * 512);
  const float4* WhBd = (const float4*)(p.Wh_d + rB * 512);
  const int ob = tid >> 2, oco = tid & 3;  // used by tid<128: 32 batch x 4 out-cols
  const int oc = cg * 4 + oco;
  const float4* oWr = (const float4*)(p.oW + oc * 512);
  float out_prev = 0.f;

  for (int k = 0; k < 1024; ++k) {
    const int t = 1023 - k;
    const int par_r = (k + 1) & 1, par_w = k & 1;
    float aA0 = biasAd, aA1 = 0.f, aB0 = biasBd, aB1 = 0.f;
    float po0 = 0.f, po1 = 0.f;

    // write out[t+1] computed last tick (no races: this tick everyone reads x[t], t < t+1,
    // and groups only touch their own batch rows)
    if (k > 0 && tid < 128)
      p.x[((bg * 32 + ob) * L_SEQ + (t + 1)) * 256 + oc] = out_prev;

    stage256(buf, xrow + t * 256, L_SEQ * 256);
    __syncthreads();
    kloop(aA0, aA1, aB0, aB1, buf, bo, WxAd, WxBd);
    __syncthreads();

    const float* hbase = p.h0g + par_r * 65536 + bg * 32 * 512;
    stage_h(buf, hbase, 512);
    __syncthreads();
    kloop(aA0, aA1, aB0, aB1, buf, bo, WhAd, WhBd);
    if (tid < 128) {  // out-proj chunk 0 (uses same staged pre-step h0)
      const float4* hb4 = (const float4*)(&buf[ob][0]);
#pragma unroll 8
      for (int j = 0; j < 64; ++j) {
        const float4 a = hb4[j], u = oWr[j];
        po0 = fmaf(a.x, u.x, po0); po1 = fmaf(a.y, u.y, po1);
        po0 = fmaf(a.z, u.z, po0); po1 = fmaf(a.w, u.w, po1);
      }
    }
    __syncthreads();
    stage_h(buf, hbase + 256, 512);
    __syncthreads();
    kloop(aA0, aA1, aB0, aB1, buf, bo, WhAd + 64, WhBd + 64);
    if (tid < 128) {  // out-proj chunk 1
      const float4* hb4 = (const float4*)(&buf[ob][0]);
#pragma unroll 8
      for (int j = 0; j < 64; ++j) {
        const float4 a = hb4[j], u = oWr[64 + j];
        po0 = fmaf(a.x, u.x, po0); po1 = fmaf(a.y, u.y, po1);
        po0 = fmaf(a.z, u.z, po0); po1 = fmaf(a.w, u.w, po1);
      }
    }

    const float accA = aA0 + aA1, accB = aB0 + aB1;
    const float gg = __shfl_xor(accA, 8);
    const float oo = __shfl_xor(accB, 8);
    if (gp == 0) {
      const float iv = sigm(accA), fv = sigm(accB), gv = tanhf(gg), ov = sigm(oo);
      cst = fmaf(fv, cst, iv * gv);
      __hip_atomic_store(p.h0g + par_w * 65536 + b * 512 + hid, ov * tanhf(cst),
                         __ATOMIC_RELAXED, __HIP_MEMORY_SCOPE_AGENT);
    }
    out_prev = po0 + po1 + p.ob[oc];
    gbar(flags, cg, tick); ++tick;
  }
  if (tid < 128)  // final output (t = 0)
    p.x[((bg * 32 + ob) * L_SEQ + 0) * 256 + oc] = out_prev;
}

// ===================== launch =====================

extern "C" void kernel_launch(void* const* d_in, const int* in_sizes, int n_in,
                              void* d_out, int out_size, void* d_ws, size_t ws_size,
                              hipStream_t stream) {
  (void)in_sizes; (void)n_in; (void)out_size; (void)ws_size;

  const float* x_in = (const float*)d_in[0];
  const float* c1w  = (const float*)d_in[1];
  const float* bn1g = (const float*)d_in[2];
  const float* bn1b = (const float*)d_in[3];
  const float* c2w  = (const float*)d_in[4];
  const float* bn2g = (const float*)d_in[5];
  const float* bn2b = (const float*)d_in[6];
  const float* c3w  = (const float*)d_in[7];
  const float* bn3g = (const float*)d_in[8];
  const float* bn3b = (const float*)d_in[9];
  const float* eWx0 = (const float*)d_in[10];
  const float* eWh0 = (const float*)d_in[11];
  const float* ebi0 = (const float*)d_in[12];
  const float* ebh0 = (const float*)d_in[13];
  // enc layer-1 params (14..17) and dec layer-1 params (22..25) are dead code
  const float* dWx0 = (const float*)d_in[18];
  const float* dWh0 = (const float*)d_in[19];
  const float* dbi0 = (const float*)d_in[20];
  const float* dbh0 = (const float*)d_in[21];
  const float* oW   = (const float*)d_in[26];
  const float* obv  = (const float*)d_in[27];

  float* out = (float*)d_out;
  float* A     = (float*)d_ws;            // conv1 out: 128*1024*32
  float* Bb    = A + 4194304;             // conv2 out: 128*1024*64
  float* stats = Bb + 8388608;            // 512 floats (sum, sumsq)
  float* h0g   = stats + 512;             // 2*128*512
  unsigned* flags = (unsigned*)(h0g + 131072);  // 4 groups x 64 uints

  // ---- conv1 + BN + ReLU ----
  hipMemsetAsync(stats, 0, 512 * sizeof(float), stream);
  conv_k<32, 32, 8><<<dim3(1, 128, 128), 256, 0, stream>>>(x_in, c1w, A, 32);
  bn_stats_k<32><<<1024, 256, 0, stream>>>(A, stats, 4194304);
  bn_norm_k<32><<<2048, 256, 0, stream>>>(A, stats, bn1g, bn1b, 1048576);

  // ---- conv2 + BN + ReLU ----
  hipMemsetAsync(stats, 0, 512 * sizeof(float), stream);
  conv_k<32, 64, 4><<<dim3(1, 256, 128), 256, 0, stream>>>(A, c2w, Bb, 64);
  bn_stats_k<64><<<1024, 256, 0, stream>>>(Bb, stats, 8388608);
  bn_norm_k<64><<<2048, 256, 0, stream>>>(Bb, stats, bn2g, bn2b, 2097152);

  // ---- conv3 + BN + ReLU (written straight into d_out; used as teacher input x) ----
  hipMemsetAsync(stats, 0, 512 * sizeof(float), stream);
  conv_k<64, 64, 4><<<dim3(4, 256, 128), 256, 0, stream>>>(Bb, c3w, out, 256);
  bn_stats_k<256><<<1024, 256, 0, stream>>>(out, stats, 33554432);
  bn_norm_k<256><<<4096, 256, 0, stream>>>(out, stats, bn3g, bn3b, 8388608);

  // ---- persistent LSTM enc+dec ----
  hipMemsetAsync(flags, 0, 256 * sizeof(unsigned), stream);
  LP lp{eWx0, eWh0, ebi0, ebh0, dWx0, dWh0, dbi0, dbh0, oW, obv, out, h0g, flags};
  void* kargs[] = {&lp};
  hipLaunchCooperativeKernel((const void*)lstm_k, dim3(256), dim3(512), kargs, 0, stream);
}

// Round 4
// 122204.626 us; speedup vs baseline: 1.8169x; 1.7113x over previous
//
#include <hip/hip_runtime.h>
#include <math.h>

#define L_SEQ 1024
#define EPSBN 1e-5f

// ===================== conv + BN (training-mode batch stats) =====================

template<int CI, int COT, int TL>
__global__ __launch_bounds__(256) void conv_k(const float* __restrict__ in,
                                              const float* __restrict__ w,
                                              float* __restrict__ out, int CO) {
  static_assert(COT * TL == 256, "block mismatch");
  __shared__ float s_in[TL + 6][CI + 1];
  const int cog = blockIdx.x, lt = blockIdx.y, b = blockIdx.z;
  const int l0 = lt * TL;
  for (int i = threadIdx.x; i < (TL + 6) * CI; i += 256) {
    const int r = i / CI, c = i - r * CI;
    const int l = l0 + r - 3;
    s_in[r][c] = (l >= 0 && l < L_SEQ) ? in[(b * L_SEQ + l) * CI + c] : 0.f;
  }
  __syncthreads();
  const int lo = threadIdx.x / COT, coo = threadIdx.x % COT;
  const int co = cog * COT + coo;
  const float* wr = w + co * (CI * 7);
  float acc = 0.f;
  for (int ci = 0; ci < CI; ++ci) {
    const float* wc = wr + ci * 7;
#pragma unroll
    for (int k = 0; k < 7; ++k) acc = fmaf(s_in[lo + k][ci], wc[k], acc);
  }
  out[(b * L_SEQ + l0 + lo) * CO + co] = acc;
}

template<int C>
__global__ __launch_bounds__(256) void bn_stats_k(const float* __restrict__ x,
                                                  float* __restrict__ sums, int n) {
  float s = 0.f, q = 0.f;
  const int stride = gridDim.x * 256;
  for (int i = blockIdx.x * 256 + threadIdx.x; i < n; i += stride) {
    const float v = x[i];
    s += v;
    q = fmaf(v, v, q);
  }
  __shared__ float ss[256], sq[256];
  ss[threadIdx.x] = s; sq[threadIdx.x] = q;
  __syncthreads();
#pragma unroll
  for (int off = 128; off >= C; off >>= 1) {
    if (threadIdx.x < off) {
      ss[threadIdx.x] += ss[threadIdx.x + off];
      sq[threadIdx.x] += sq[threadIdx.x + off];
    }
    __syncthreads();
  }
  if (threadIdx.x < C) {
    atomicAdd(&sums[threadIdx.x], ss[threadIdx.x]);
    atomicAdd(&sums[256 + threadIdx.x], sq[threadIdx.x]);
  }
}

template<int C>
__global__ __launch_bounds__(256) void bn_norm_k(float* __restrict__ x,
                                                 const float* __restrict__ sums,
                                                 const float* __restrict__ g,
                                                 const float* __restrict__ bt, int n4) {
  const float invN = 1.f / 131072.f;  // B*L
  const int stride = gridDim.x * 256;
  for (int i = blockIdx.x * 256 + threadIdx.x; i < n4; i += stride) {
    float4 v = ((const float4*)x)[i];
    const int c0 = (i * 4) % C;
    float r[4] = {v.x, v.y, v.z, v.w};
#pragma unroll
    for (int j = 0; j < 4; ++j) {
      const int c = c0 + j;
      const float m = sums[c] * invN;
      const float var = fmaf(-m, m, sums[256 + c] * invN);
      const float y = g[c] * (r[j] - m) * rsqrtf(var + EPSBN) + bt[c];
      r[j] = fmaxf(y, 0.f);
    }
    ((float4*)x)[i] = make_float4(r[0], r[1], r[2], r[3]);
  }
}

// ===================== per-timestep LSTM kernel (layer 1 is dead code) =====================
// One launch per timestep: kernel boundaries provide device-wide coherence for h/c,
// so no atomics/fences/barrier games at all.
// Grid: 256 gate WGs (+32 out-proj WGs for decoder steps). 512 threads.
//   gate WG tile: 8 batches x 32 hid x 4 gates; 2 hid per thread.
//   out WG tile : 4 batches x 256 out-cols; 2 oc per thread. out[t] is staged in Ostg
//   and flushed to d_out[t+1] by the NEXT step (avoids x-read/out-write race on d_out).

__device__ __forceinline__ float sigm(float v) { return 1.f / (1.f + __expf(-v)); }

#define FMA8(a, u, v)                                        \
  acc0 = fmaf(a.x, u.x, acc0); acc1 = fmaf(a.x, v.x, acc1);  \
  acc0 = fmaf(a.y, u.y, acc0); acc1 = fmaf(a.y, v.y, acc1);  \
  acc0 = fmaf(a.z, u.z, acc0); acc1 = fmaf(a.z, v.z, acc1);  \
  acc0 = fmaf(a.w, u.w, acc0); acc1 = fmaf(a.w, v.w, acc1);

__global__ __launch_bounds__(512) void step_k(const float* __restrict__ Wih,
                                              const float* __restrict__ Whh,
                                              const float* __restrict__ bi,
                                              const float* __restrict__ bh,
                                              const float* __restrict__ xt,   // x + t*256
                                              const float* __restrict__ Hin,
                                              float* __restrict__ Hout,
                                              float* __restrict__ C,
                                              const float* __restrict__ oW,
                                              const float* __restrict__ ob,
                                              float* __restrict__ Ostg,
                                              float* __restrict__ outw) {     // d_out + (t+1)*256 or null
  const int tid = threadIdx.x;
  if (blockIdx.x < 256) {
    // ---------------- gate WGs ----------------
    __shared__ float act[8][772];       // [batch][0:256 x | 256:768 h]; 772%32==4 -> conflict-free
    __shared__ float gb[8][32][4];      // gate combine buffer
    const int bT = blockIdx.x >> 4, hT = blockIdx.x & 15;
    {   // stage x tile: 8 rows x 64 float4
      const int r = tid >> 6, c4 = (tid & 63) << 2;
      *(float4*)&act[r][c4] = *(const float4*)(xt + (bT * 8 + r) * (L_SEQ * 256) + c4);
    }
    {   // stage h tile: 8 rows x 128 float4 (2 per thread)
      int r = tid >> 7, c4 = (tid & 127) << 2;
      *(float4*)&act[r][256 + c4] = *(const float4*)(Hin + (bT * 8 + r) * 512 + c4);
      r += 4;
      *(float4*)&act[r][256 + c4] = *(const float4*)(Hin + (bT * 8 + r) * 512 + c4);
    }
    __syncthreads();

    const int g = tid >> 7, h16 = (tid >> 3) & 15, bo = tid & 7;
    const int hid0 = hT * 32 + h16 * 2;
    const int row0 = g * 512 + hid0;
    float acc0 = bi[row0] + bh[row0];
    float acc1 = bi[row0 + 1] + bh[row0 + 1];

    const float4* a4 = (const float4*)&act[bo][0];
    const float4* u4 = (const float4*)(Wih + row0 * 256);
    const float4* v4 = (const float4*)(Wih + (row0 + 1) * 256);
#pragma unroll 8
    for (int k = 0; k < 64; ++k) { const float4 a = a4[k], u = u4[k], v = v4[k]; FMA8(a, u, v) }

    const float4* b4 = (const float4*)&act[bo][256];
    const float4* p4 = (const float4*)(Whh + row0 * 512);
    const float4* q4 = (const float4*)(Whh + (row0 + 1) * 512);
#pragma unroll 8
    for (int k = 0; k < 128; ++k) { const float4 a = b4[k], u = p4[k], v = q4[k]; FMA8(a, u, v) }

    gb[bo][h16 * 2][g] = acc0;
    gb[bo][h16 * 2 + 1][g] = acc1;
    __syncthreads();

    if (g == 0) {  // tid < 128: combine 4 gates for 2 hids, update c & h
      const int b = bT * 8 + bo;
#pragma unroll
      for (int j = 0; j < 2; ++j) {
        const int hh = h16 * 2 + j, hid = hT * 32 + hh;
        const float iv = sigm(gb[bo][hh][0]);
        const float fv = sigm(gb[bo][hh][1]);
        const float gv = tanhf(gb[bo][hh][2]);
        const float ov = sigm(gb[bo][hh][3]);
        const float cn = fmaf(fv, C[b * 512 + hid], iv * gv);
        C[b * 512 + hid] = cn;
        Hout[b * 512 + hid] = ov * tanhf(cn);
      }
    }
  } else {
    // ---------------- out-proj WGs (decoder only; blockIdx 256..287) ----------------
    __shared__ float hrow[4][516];
    const int oT = blockIdx.x - 256;
    {   // stage 4 h rows (512 float4, 1 per thread)
      const int r = tid >> 7, c4 = (tid & 127) << 2;
      *(float4*)&hrow[r][c4] = *(const float4*)(Hin + (oT * 4 + r) * 512 + c4);
    }
    __syncthreads();
    const int bo = tid >> 7, oc0 = (tid & 127) * 2;
    const int b = oT * 4 + bo;
    float acc0 = ob[oc0], acc1 = ob[oc0 + 1];
    const float4* a4 = (const float4*)&hrow[bo][0];
    const float4* u4 = (const float4*)(oW + oc0 * 512);
    const float4* v4 = (const float4*)(oW + (oc0 + 1) * 512);
#pragma unroll 8
    for (int k = 0; k < 128; ++k) { const float4 a = a4[k], u = u4[k], v = v4[k]; FMA8(a, u, v) }

    // flush out[t+1] computed by the previous step, then stage out[t]
    if (outw) {
      outw[b * (L_SEQ * 256) + oc0]     = Ostg[b * 256 + oc0];
      outw[b * (L_SEQ * 256) + oc0 + 1] = Ostg[b * 256 + oc0 + 1];
    }
    Ostg[b * 256 + oc0] = acc0;
    Ostg[b * 256 + oc0 + 1] = acc1;
  }
}

__global__ __launch_bounds__(256) void flush_k(float* __restrict__ out,
                                               const float* __restrict__ Ostg) {
  const int i = blockIdx.x * 256 + threadIdx.x;   // 128*256 elements
  const int b = i >> 8, oc = i & 255;
  out[b * (L_SEQ * 256) + oc] = Ostg[i];          // d_out[b][0][oc]
}

// ===================== launch =====================

extern "C" void kernel_launch(void* const* d_in, const int* in_sizes, int n_in,
                              void* d_out, int out_size, void* d_ws, size_t ws_size,
                              hipStream_t stream) {
  (void)in_sizes; (void)n_in; (void)out_size; (void)ws_size;

  const float* x_in = (const float*)d_in[0];
  const float* c1w  = (const float*)d_in[1];
  const float* bn1g = (const float*)d_in[2];
  const float* bn1b = (const float*)d_in[3];
  const float* c2w  = (const float*)d_in[4];
  const float* bn2g = (const float*)d_in[5];
  const float* bn2b = (const float*)d_in[6];
  const float* c3w  = (const float*)d_in[7];
  const float* bn3g = (const float*)d_in[8];
  const float* bn3b = (const float*)d_in[9];
  const float* eWx0 = (const float*)d_in[10];
  const float* eWh0 = (const float*)d_in[11];
  const float* ebi0 = (const float*)d_in[12];
  const float* ebh0 = (const float*)d_in[13];
  // enc layer-1 params (14..17) and dec layer-1 params (22..25) are dead code
  const float* dWx0 = (const float*)d_in[18];
  const float* dWh0 = (const float*)d_in[19];
  const float* dbi0 = (const float*)d_in[20];
  const float* dbh0 = (const float*)d_in[21];
  const float* oW   = (const float*)d_in[26];
  const float* obv  = (const float*)d_in[27];

  float* out = (float*)d_out;
  float* A     = (float*)d_ws;            // conv1 out: 128*1024*32
  float* Bb    = A + 4194304;             // conv2 out: 128*1024*64
  float* stats = Bb + 8388608;            // 512 floats (sum, sumsq)
  float* H0    = stats + 512;             // 128*512
  float* H1    = H0 + 65536;
  float* Cst   = H1 + 65536;              // 128*512 cell state
  float* Ostg  = Cst + 65536;             // 128*256 out-proj staging

  // ---- conv1 + BN + ReLU ----
  hipMemsetAsync(stats, 0, 512 * sizeof(float), stream);
  conv_k<32, 32, 8><<<dim3(1, 128, 128), 256, 0, stream>>>(x_in, c1w, A, 32);
  bn_stats_k<32><<<1024, 256, 0, stream>>>(A, stats, 4194304);
  bn_norm_k<32><<<2048, 256, 0, stream>>>(A, stats, bn1g, bn1b, 1048576);

  // ---- conv2 + BN + ReLU ----
  hipMemsetAsync(stats, 0, 512 * sizeof(float), stream);
  conv_k<32, 64, 4><<<dim3(1, 256, 128), 256, 0, stream>>>(A, c2w, Bb, 64);
  bn_stats_k<64><<<1024, 256, 0, stream>>>(Bb, stats, 8388608);
  bn_norm_k<64><<<2048, 256, 0, stream>>>(Bb, stats, bn2g, bn2b, 2097152);

  // ---- conv3 + BN + ReLU (written straight into d_out; used as teacher input x) ----
  hipMemsetAsync(stats, 0, 512 * sizeof(float), stream);
  conv_k<64, 64, 4><<<dim3(4, 256, 128), 256, 0, stream>>>(Bb, c3w, out, 256);
  bn_stats_k<256><<<1024, 256, 0, stream>>>(out, stats, 33554432);
  bn_norm_k<256><<<4096, 256, 0, stream>>>(out, stats, bn3g, bn3b, 8388608);

  // ---- LSTM: one kernel per timestep; kernel boundary = global barrier ----
  hipMemsetAsync(H0, 0, 65536 * sizeof(float), stream);   // h init (enc step 0 reads H0)
  hipMemsetAsync(Cst, 0, 65536 * sizeof(float), stream);  // c init

  float* Hb[2] = {H0, H1};
  // encoder: 1024 steps, no out-proj WGs
  for (int k = 0; k < 1024; ++k) {
    step_k<<<256, 512, 0, stream>>>(eWx0, eWh0, ebi0, ebh0, out + k * 256,
                                    Hb[k & 1], Hb[(k + 1) & 1], Cst,
                                    oW, obv, Ostg, nullptr);
  }
  // decoder: 1024 steps (t = 1023..0), 32 extra out-proj WGs
  for (int j = 0; j < 1024; ++j) {
    const int t = 1023 - j;
    step_k<<<288, 512, 0, stream>>>(dWx0, dWh0, dbi0, dbh0, out + t * 256,
                                    Hb[j & 1], Hb[(j + 1) & 1], Cst,
                                    oW, obv, Ostg,
                                    j ? (out + (t + 1) * 256) : nullptr);
  }
  flush_k<<<128, 256, 0, stream>>>(out, Ostg);  // d_out[:, 0, :]
}